// Round 6
// baseline (901.355 us; speedup 1.0000x reference)
//
#include <hip/hip_runtime.h>
#include <hip/hip_bf16.h>

typedef __hip_bfloat16 bf16;
typedef float v4f __attribute__((ext_vector_type(4)));
typedef short v8s __attribute__((ext_vector_type(8)));

#define KSEL 307

__device__ static inline void async16(bf16* lds, const bf16* g) {
    __builtin_amdgcn_global_load_lds(
        (const __attribute__((address_space(1))) void*)g,
        (__attribute__((address_space(3))) void*)lds, 16, 0, 0);
}

__device__ static inline unsigned short f2bu(float f) {
    __hip_bfloat16 h = __float2bfloat16(f);
    return *reinterpret_cast<unsigned short*>(&h);
}

__device__ static inline unsigned pk2(float a, float b) {
    __hip_bfloat162 h = __float22bfloat162_rn(make_float2(a, b));
    return *reinterpret_cast<unsigned*>(&h);
}

// tanh-approx gelu via hardware exp: ~8 VALU ops vs ~35 for erff.
__device__ static inline float gelu_f(float v) {
    float c = v * fmaf(v * v, 0.0356774081f, 0.7978845608f);
    return v / (1.0f + __expf(-2.0f * c));
}

// ---------------- fp32 -> bf16 convert, 7 segments in one launch ----------------
struct F2BP { const float* src[7]; bf16* dst[7]; int n4[7]; };

__global__ void __launch_bounds__(256) f2b_multi(F2BP p) {
    int s = blockIdx.y;
    const float* __restrict__ in = p.src[s];
    bf16* __restrict__ out = p.dst[s];
    int n4 = p.n4[s];
    for (int i = blockIdx.x * 256 + threadIdx.x; i < n4; i += gridDim.x * 256) {
        float4 v = ((const float4*)in)[i];
        ushort4 u = make_ushort4(f2bu(v.x), f2bu(v.y), f2bu(v.z), f2bu(v.w));
        ((ushort4*)out)[i] = u;
    }
}

// ---------------- LayerNorm (row of 1024) ----------------
__global__ void __launch_bounds__(256) ln_kernel(const float* __restrict__ x,
                                                 const float* __restrict__ g,
                                                 const float* __restrict__ be,
                                                 bf16* __restrict__ out) {
    int row = blockIdx.x;
    int tid = threadIdx.x;
    const float* xr = x + row * 1024;
    float4 v = ((const float4*)xr)[tid];
    float s = v.x + v.y + v.z + v.w;
    float s2 = v.x*v.x + v.y*v.y + v.z*v.z + v.w*v.w;
    for (int off = 32; off > 0; off >>= 1) {
        s  += __shfl_down(s, off);
        s2 += __shfl_down(s2, off);
    }
    __shared__ float sh[4], sh2[4];
    int w = tid >> 6;
    if ((tid & 63) == 0) { sh[w] = s; sh2[w] = s2; }
    __syncthreads();
    float mean = (sh[0]+sh[1]+sh[2]+sh[3]) * (1.0f / 1024.f);
    float ms   = (sh2[0]+sh2[1]+sh2[2]+sh2[3]) * (1.0f / 1024.f);
    float var  = ms - mean*mean;
    float rs   = rsqrtf(var + 1e-5f);
    float4 gg = ((const float4*)g)[tid];
    float4 bb = ((const float4*)be)[tid];
    ushort4 o = make_ushort4(
        f2bu((v.x-mean)*rs*gg.x + bb.x),
        f2bu((v.y-mean)*rs*gg.y + bb.y),
        f2bu((v.z-mean)*rs*gg.z + bb.z),
        f2bu((v.w-mean)*rs*gg.w + bb.w));
    ((ushort4*)out)[row * 256 + tid] = o;
}

// ---------------- top-k threshold + masked softmax, ONE ROW PER WAVE ----------
// Ballot-bisection: identical maximal 16-bit threshold, zero LDS/atomics.
__global__ void __launch_bounds__(256) topk_softmax(unsigned short* __restrict__ scb,
                                                    float* __restrict__ out) {
    const int tid = threadIdx.x;
    const int wid = tid >> 6, lane = tid & 63;
    const long long row = (long long)blockIdx.x * 4 + wid;
    unsigned short* pb = scb + row * 1024;
    float* po = out + row * 1024;

    unsigned key[16];
    float v[16];
#pragma unroll
    for (int j = 0; j < 4; ++j) {
        ushort4 t = *(const ushort4*)(pb + lane * 4 + j * 256);
        key[j*4+0] = t.x; key[j*4+1] = t.y; key[j*4+2] = t.z; key[j*4+3] = t.w;
    }
#pragma unroll
    for (int j = 0; j < 16; ++j) {
        unsigned u = key[j];
        v[j] = __uint_as_float(u << 16);            // exact bf16 -> f32
        key[j] = (u & 0x8000u) ? (0xFFFFu & ~u) : (u | 0x8000u);
    }

    unsigned lo = 0, hi = 65536;
#pragma unroll
    for (int it = 0; it < 16; ++it) {
        unsigned mid = (lo + hi) >> 1;
        int cnt = 0;
#pragma unroll
        for (int j = 0; j < 16; ++j)
            cnt += (int)__popcll(__ballot(key[j] >= mid));
        if (cnt >= KSEL) lo = mid; else hi = mid;   // cnt is wave-uniform
    }
    const unsigned prefix = lo;

    float mx = v[0];
#pragma unroll
    for (int j = 1; j < 16; ++j) mx = fmaxf(mx, v[j]);
#pragma unroll
    for (int off = 32; off > 0; off >>= 1) mx = fmaxf(mx, __shfl_xor(mx, off));
    float sum = 0.f;
#pragma unroll
    for (int j = 0; j < 16; ++j) {
        bool sel = key[j] >= prefix;
        v[j] = sel ? __expf(v[j] - mx) : 0.f;
        sum += v[j];
    }
#pragma unroll
    for (int off = 32; off > 0; off >>= 1) sum += __shfl_xor(sum, off);
    float inv = 1.0f / sum;
#pragma unroll
    for (int j = 0; j < 4; ++j) {
        float4 o;
        o.x = v[j*4+0]*inv; o.y = v[j*4+1]*inv; o.z = v[j*4+2]*inv; o.w = v[j*4+3]*inv;
        *(float4*)(po + lane * 4 + j * 256) = o;
        uint2 u;                                    // bf16 copy for attnv
        u.x = pk2(o.x, o.y); u.y = pk2(o.z, o.w);
        *(uint2*)(pb + lane * 4 + j * 256) = u;
    }
}

// ---------------- QK^T (K=64): stage everything up front, one barrier, 32 MFMA.
__global__ void __launch_bounds__(256) qk_kernel(const bf16* __restrict__ Q,
                                                 const bf16* __restrict__ Kb,
                                                 bf16* __restrict__ Cb) {
    __shared__ __align__(16) bf16 As[2][128 * 32];
    __shared__ __align__(16) bf16 Bs[2][128 * 32];
    const int z = blockIdx.z, b = z >> 4, h = z & 15;
    const int offA = b * 1048576 + h * 64;
    const int offC = z * 1048576;
    const int tid = threadIdx.x;
    const int w = tid >> 6, lane = tid & 63;
    const int tm = blockIdx.y * 128, tn = blockIdx.x * 128;
    const int q = lane >> 4, m16 = lane & 15;
    const int r0 = (w >> 1) * 64, c0 = (w & 1) * 64;
    const int srow = lane >> 2;
    const int scol = ((lane & 3) ^ ((lane >> 3) & 3)) * 8;
    const int sq = q ^ ((m16 >> 1) & 3);

    const bf16* Ab = Q  + offA + (tm + w * 16 + srow) * 1024 + scol;
    const bf16* Bb = Kb + offA + (tn + w * 16 + srow) * 1024 + scol;

#pragma unroll
    for (int s = 0; s < 2; ++s) {
        async16(&As[s][(w * 16) * 32],       Ab + s * 32);
        async16(&As[s][(64 + w * 16) * 32],  Ab + 64 * 1024 + s * 32);
        async16(&Bs[s][(w * 16) * 32],       Bb + s * 32);
        async16(&Bs[s][(64 + w * 16) * 32],  Bb + 64 * 1024 + s * 32);
    }
    __syncthreads();

    v4f acc[4][4];
#pragma unroll
    for (int i = 0; i < 4; ++i)
#pragma unroll
        for (int j = 0; j < 4; ++j) acc[i][j] = (v4f){0.f, 0.f, 0.f, 0.f};

#pragma unroll
    for (int s = 0; s < 2; ++s) {
        v8s af[4], bfr[4];
#pragma unroll
        for (int i = 0; i < 4; ++i)
            af[i] = *(const v8s*)&As[s][(r0 + 16 * i + m16) * 32 + sq * 8];
#pragma unroll
        for (int j = 0; j < 4; ++j)
            bfr[j] = *(const v8s*)&Bs[s][(c0 + 16 * j + m16) * 32 + sq * 8];
#pragma unroll
        for (int i = 0; i < 4; ++i)
#pragma unroll
            for (int j = 0; j < 4; ++j)
                acc[i][j] = __builtin_amdgcn_mfma_f32_16x16x32_bf16(af[i], bfr[j], acc[i][j], 0, 0, 0);
    }

#pragma unroll
    for (int i = 0; i < 4; ++i)
#pragma unroll
        for (int r = 0; r < 4; ++r) {
            int row = tm + r0 + 16 * i + q * 4 + r;
            int rowbase = offC + row * 1024 + tn + c0 + m16;
#pragma unroll
            for (int j = 0; j < 4; ++j)
                Cb[rowbase + 16 * j] = __float2bfloat16(acc[i][j][r] * 0.125f);
        }
}

// ---------------- gemm128p: 128x128, 8 waves, 4-deep LDS ring, counted vmcnt(2),
// one barrier per K-tile, T2 source-swizzle, XCD swizzle. QKV/VT/Wo/W1/W2.
template<int K, int LDA, int LDB, int LDC, int BMODE, int ACT, int SWZ>
__global__ void __launch_bounds__(512, 2) gemm128p(const bf16* __restrict__ A,
                                                   const bf16* __restrict__ B,
                                                   float* __restrict__ Cf,
                                                   bf16* __restrict__ Cb,
                                                   const float* __restrict__ bias,
                                                   const float* __restrict__ resid) {
    __shared__ __align__(16) bf16 As[4][128 * 32];
    __shared__ __align__(16) bf16 Bs[4][128 * 32];

    constexpr int nt = K / 32;
    static_assert(nt >= 4, "K >= 128");

    const int tid = threadIdx.x;
    const int w = tid >> 6, lane = tid & 63;
    const int wr = w >> 2, wc = w & 3;
    const int q = lane >> 4, m16 = lane & 15;

    int bx = blockIdx.x, by = blockIdx.y;
    if (SWZ) {
        int nx = gridDim.x;
        int bid = by * nx + bx;
        int nwg = nx * gridDim.y;
        int nb = (bid & 7) * (nwg >> 3) + (bid >> 3);
        bx = nb % nx; by = nb / nx;
    }
    const int tm = by * 128, tn = bx * 128;

    const int srow = lane >> 2;
    const int scol = ((lane & 3) ^ ((lane >> 3) & 3)) * 8;
    const bf16* Ag = A + (tm + w * 16 + srow) * LDA + scol;
    const bf16* Bg = B + (tn + w * 16 + srow) * LDB + scol;

    v4f acc[4][2];
#pragma unroll
    for (int i = 0; i < 4; ++i)
#pragma unroll
        for (int j = 0; j < 2; ++j) acc[i][j] = (v4f){0.f, 0.f, 0.f, 0.f};

    const int sq = q ^ ((m16 >> 1) & 3);
    const int aoff = (wr * 64 + m16) * 32 + sq * 8;
    const int boff = (wc * 32 + m16) * 32 + sq * 8;

#pragma unroll
    for (int t = 0; t < 2; ++t) {
        async16(&As[t][(w * 16) * 32], Ag + t * 32);
        async16(&Bs[t][(w * 16) * 32], Bg + t * 32);
    }
    asm volatile("s_waitcnt vmcnt(2)" ::: "memory");
    __builtin_amdgcn_s_barrier();
    __builtin_amdgcn_sched_barrier(0);

#pragma unroll 1
    for (int t = 0; t < nt; ++t) {
        const int cur = t & 3, pre = (t + 2) & 3;
        const int kt = (t + 2 < nt) ? (t + 2) : 0;
        v8s af[4], bfr[2];
#pragma unroll
        for (int i = 0; i < 4; ++i)
            af[i] = *(const v8s*)&As[cur][aoff + i * 512];
#pragma unroll
        for (int j = 0; j < 2; ++j)
            bfr[j] = *(const v8s*)&Bs[cur][boff + j * 512];
        async16(&As[pre][(w * 16) * 32], Ag + kt * 32);
        async16(&Bs[pre][(w * 16) * 32], Bg + kt * 32);
        asm volatile("s_waitcnt lgkmcnt(0)" ::: "memory");
        __builtin_amdgcn_sched_barrier(0);
        __builtin_amdgcn_s_setprio(1);
#pragma unroll
        for (int i = 0; i < 4; ++i)
#pragma unroll
            for (int j = 0; j < 2; ++j)
                acc[i][j] = __builtin_amdgcn_mfma_f32_16x16x32_bf16(af[i], bfr[j], acc[i][j], 0, 0, 0);
        __builtin_amdgcn_s_setprio(0);
        __builtin_amdgcn_sched_barrier(0);
        asm volatile("s_waitcnt vmcnt(2)" ::: "memory");
        __builtin_amdgcn_sched_barrier(0);
        __builtin_amdgcn_s_barrier();
        __builtin_amdgcn_sched_barrier(0);
    }
    asm volatile("s_waitcnt vmcnt(0)" ::: "memory");

    float bc[2];
#pragma unroll
    for (int j = 0; j < 2; ++j)
        bc[j] = (BMODE == 1) ? bias[tn + wc * 32 + 16 * j + m16] : 0.f;

#pragma unroll
    for (int i = 0; i < 4; ++i) {
#pragma unroll
        for (int r = 0; r < 4; ++r) {
            int row = tm + wr * 64 + 16 * i + q * 4 + r;
            float br = (BMODE == 2) ? bias[row] : 0.f;
            int rowbase = row * LDC + tn + wc * 32 + m16;
#pragma unroll
            for (int j = 0; j < 2; ++j) {
                float v = acc[i][j][r] + bc[j] + br;
                if (ACT) v = gelu_f(v);
                int idx = rowbase + 16 * j;
                if (resid) v += resid[idx];
                if (Cf) Cf[idx] = v;
                if (Cb) Cb[idx] = __float2bfloat16(v);
            }
        }
    }
}

// ---------------- 256x256 GEMM (Wm): one-phase-ahead register pipelining.
// Phase A consumes af/bfr (read during previous tile's phase B) and issues af2
// under the MFMA with counted lgkmcnt(4); phase B consumes af2/bfr and re-reads
// af/bfr (same registers, WAR-ordered after the MFMA) for the next tile from
// slot t+1 (safe: barrier #1 follows every wave's vmcnt(2)-wait for t+1).
// LDS drain now overlaps MFMA instead of serializing with it.
template<int K, int LDA, int LDB, int LDC>
__global__ void __launch_bounds__(512, 2) gemm256(const bf16* __restrict__ A,
                                                  const bf16* __restrict__ B,
                                                  bf16* __restrict__ C,
                                                  const float* __restrict__ bias) {
    __shared__ __align__(16) bf16 As[4][256 * 32];
    __shared__ __align__(16) bf16 Bs[4][256 * 32];

    constexpr int nt = K / 32;
    static_assert(nt >= 4 && (nt % 4) == 0, "K must be multiple of 128");

    const int tid = threadIdx.x;
    const int w = tid >> 6, lane = tid & 63;
    const int wm = w >> 2, wn = w & 3;
    const int q = lane >> 4, m16 = lane & 15;

    int bid = blockIdx.y * 16 + blockIdx.x;
    int xcd = bid & 7, inner = bid >> 3;
    int by = (xcd & 3) * 4 + (inner & 3);
    int bx = (xcd >> 2) * 8 + (inner >> 2);
    const int tm = by * 256, tn = bx * 256;

    const int srow = lane >> 2;
    const int scol = ((lane & 3) ^ ((lane >> 3) & 3)) * 8;
    const bf16* Ag = A + (tm + w * 32 + srow) * LDA + scol;
    const bf16* Bg = B + (tn + w * 32 + srow) * LDB + scol;

    v4f acc[8][4];
#pragma unroll
    for (int i = 0; i < 8; ++i)
#pragma unroll
        for (int j = 0; j < 4; ++j) acc[i][j] = (v4f){0.f, 0.f, 0.f, 0.f};

    const int sq = q ^ ((m16 >> 1) & 3);
    const int aoff = (wm * 128 + m16) * 32 + sq * 8;
    const int boff = (wn * 64 + m16) * 32 + sq * 8;

    // prologue: stage tiles 0,1; wait tile 0; pre-read tile 0's phase-A regs
#pragma unroll
    for (int t = 0; t < 2; ++t) {
        async16(&As[t][(w * 32) * 32],      Ag + t * 32);
        async16(&As[t][(w * 32 + 16) * 32], Ag + 16 * LDA + t * 32);
        async16(&Bs[t][(w * 32) * 32],      Bg + t * 32);
        async16(&Bs[t][(w * 32 + 16) * 32], Bg + 16 * LDB + t * 32);
    }
    asm volatile("s_waitcnt vmcnt(4)" ::: "memory");   // tile 0 landed
    __builtin_amdgcn_s_barrier();
    __builtin_amdgcn_sched_barrier(0);

    v8s af[4], bfr[4];
#pragma unroll
    for (int i = 0; i < 4; ++i)
        af[i] = *(const v8s*)&As[0][aoff + i * 512];
#pragma unroll
    for (int j = 0; j < 4; ++j)
        bfr[j] = *(const v8s*)&Bs[0][boff + j * 512];
    __builtin_amdgcn_sched_barrier(0);

#pragma unroll 1
    for (int t = 0; t < nt; ++t) {
        const int cur = t & 3, nxt = (t + 1) & 3, pre = (t + 2) & 3;
        const int kt = (t + 2 < nt) ? (t + 2) : 0;

        // ---- phase A: consume af/bfr; issue af2 under the MFMA ----
        v8s af2[4];
#pragma unroll
        for (int i = 0; i < 4; ++i)
            af2[i] = *(const v8s*)&As[cur][aoff + 2048 + i * 512];
        async16(&As[pre][(w * 32) * 32],      Ag + kt * 32);
        async16(&As[pre][(w * 32 + 16) * 32], Ag + 16 * LDA + kt * 32);
        asm volatile("s_waitcnt lgkmcnt(4)" ::: "memory");   // af,bfr ready; af2 in flight
        __builtin_amdgcn_sched_barrier(0);
        __builtin_amdgcn_s_setprio(1);
#pragma unroll
        for (int i = 0; i < 4; ++i)
#pragma unroll
            for (int j = 0; j < 4; ++j)
                acc[i][j] = __builtin_amdgcn_mfma_f32_16x16x32_bf16(af[i], bfr[j], acc[i][j], 0, 0, 0);
        __builtin_amdgcn_s_setprio(0);
        __builtin_amdgcn_sched_barrier(0);
        asm volatile("s_waitcnt vmcnt(2)" ::: "memory");     // tile t+1 landed; t+2 A in flight
        __builtin_amdgcn_sched_barrier(0);
        __builtin_amdgcn_s_barrier();                        // #1: t+1 globally visible
        __builtin_amdgcn_sched_barrier(0);

        // ---- phase B: consume af2/bfr; pre-read next tile's af (then bfr) ----
#pragma unroll
        for (int i = 0; i < 4; ++i)
            af[i] = *(const v8s*)&As[nxt][aoff + i * 512];
        async16(&Bs[pre][(w * 32) * 32],      Bg + kt * 32);
        async16(&Bs[pre][(w * 32 + 16) * 32], Bg + 16 * LDB + kt * 32);
        asm volatile("s_waitcnt lgkmcnt(4)" ::: "memory");   // af2 ready; new af in flight
        __builtin_amdgcn_sched_barrier(0);
        __builtin_amdgcn_s_setprio(1);
#pragma unroll
        for (int i = 0; i < 4; ++i)
#pragma unroll
            for (int j = 0; j < 4; ++j)
                acc[i + 4][j] = __builtin_amdgcn_mfma_f32_16x16x32_bf16(af2[i], bfr[j], acc[i + 4][j], 0, 0, 0);
        __builtin_amdgcn_s_setprio(0);
        __builtin_amdgcn_sched_barrier(0);
#pragma unroll
        for (int j = 0; j < 4; ++j)                          // next tile's bfr (WAR after MFMA)
            bfr[j] = *(const v8s*)&Bs[nxt][boff + j * 512];
        __builtin_amdgcn_sched_barrier(0);
        __builtin_amdgcn_s_barrier();                        // #2: end of tile
        __builtin_amdgcn_sched_barrier(0);
    }
    asm volatile("s_waitcnt vmcnt(0) lgkmcnt(0)" ::: "memory");

    float bc[4];
#pragma unroll
    for (int j = 0; j < 4; ++j)
        bc[j] = bias[tn + wn * 64 + 16 * j + m16];

#pragma unroll
    for (int i = 0; i < 8; ++i) {
#pragma unroll
        for (int r = 0; r < 4; ++r) {
            int row = tm + wm * 128 + 16 * i + q * 4 + r;
            int rowbase = row * LDC + tn + wn * 64 + m16;
#pragma unroll
            for (int j = 0; j < 4; ++j) {
                float v = acc[i][j][r] + bc[j];
                v = gelu_f(v);
                C[rowbase + 16 * j] = __float2bfloat16(v);
            }
        }
    }
}

// ---------------- attnV (bf16 P): 4-deep ring, counted vmcnt(3), 1 barrier/tile
__global__ void __launch_bounds__(256) attnv_kernel(const bf16* __restrict__ P,
                                                    const bf16* __restrict__ VT,
                                                    bf16* __restrict__ out) {
    __shared__ __align__(16) bf16 As[4][128 * 32];
    __shared__ __align__(16) bf16 Bs[4][64 * 32];
    int z = blockIdx.z, b = z >> 4, h = z & 15;
    int tid = threadIdx.x, w = tid >> 6, lane = tid & 63;
    int q = lane >> 4, m16 = lane & 15;
    int srow = lane >> 2;
    int scol = ((lane & 3) ^ ((lane >> 3) & 3)) * 8;
    const int sq = q ^ ((m16 >> 1) & 3);

    const bf16* Ab = P + z * 1048576 + (blockIdx.y * 128 + w * 16 + srow) * 1024 + scol;
    const bf16* Bb = VT + (h * 64 + w * 16 + srow) * 4096 + b * 1024 + scol;

    v4f acc[2][4];
#pragma unroll
    for (int i = 0; i < 2; ++i)
#pragma unroll
        for (int j = 0; j < 4; ++j) acc[i][j] = (v4f){0.f, 0.f, 0.f, 0.f};

    const int aoff = (w * 32 + m16) * 32 + sq * 8;
    const int boff = (m16) * 32 + sq * 8;

#pragma unroll
    for (int t = 0; t < 2; ++t) {
        async16(&As[t][(w * 16) * 32],        Ab + t * 32);
        async16(&As[t][(64 + w * 16) * 32],   Ab + 64 * 1024 + t * 32);
        async16(&Bs[t][(w * 16) * 32],        Bb + t * 32);
    }
    asm volatile("s_waitcnt vmcnt(3)" ::: "memory");
    __builtin_amdgcn_s_barrier();
    __builtin_amdgcn_sched_barrier(0);

#pragma unroll 1
    for (int t = 0; t < 32; ++t) {
        const int cur = t & 3, pre = (t + 2) & 3;
        const int kt = (t + 2 < 32) ? (t + 2) : 0;
        v8s af[2], bfr[4];
        af[0] = *(const v8s*)&As[cur][aoff];
        af[1] = *(const v8s*)&As[cur][aoff + 512];
#pragma unroll
        for (int j = 0; j < 4; ++j)
            bfr[j] = *(const v8s*)&Bs[cur][boff + j * 512];
        async16(&As[pre][(w * 16) * 32],      Ab + kt * 32);
        async16(&As[pre][(64 + w * 16) * 32], Ab + 64 * 1024 + kt * 32);
        async16(&Bs[pre][(w * 16) * 32],      Bb + kt * 32);
        asm volatile("s_waitcnt lgkmcnt(0)" ::: "memory");
        __builtin_amdgcn_sched_barrier(0);
        __builtin_amdgcn_s_setprio(1);
#pragma unroll
        for (int i = 0; i < 2; ++i)
#pragma unroll
            for (int j = 0; j < 4; ++j)
                acc[i][j] = __builtin_amdgcn_mfma_f32_16x16x32_bf16(af[i], bfr[j], acc[i][j], 0, 0, 0);
        __builtin_amdgcn_s_setprio(0);
        __builtin_amdgcn_sched_barrier(0);
        asm volatile("s_waitcnt vmcnt(3)" ::: "memory");
        __builtin_amdgcn_sched_barrier(0);
        __builtin_amdgcn_s_barrier();
        __builtin_amdgcn_sched_barrier(0);
    }
    asm volatile("s_waitcnt vmcnt(0)" ::: "memory");

    int orow0 = b * 1024 + blockIdx.y * 128 + w * 32;
#pragma unroll
    for (int i = 0; i < 2; ++i)
#pragma unroll
        for (int r = 0; r < 4; ++r) {
            int row = orow0 + 16 * i + q * 4 + r;
#pragma unroll
            for (int j = 0; j < 4; ++j) {
                int col = h * 64 + 16 * j + m16;
                out[row * 1024 + col] = __float2bfloat16(acc[i][j][r]);
            }
        }
}

// ---------------- host ----------------
extern "C" void kernel_launch(void* const* d_in, const int* in_sizes, int n_in,
                              void* d_out, int out_size, void* d_ws, size_t ws_size,
                              hipStream_t stream) {
    (void)in_sizes; (void)n_in; (void)out_size; (void)ws_size;
    const float* x  = (const float*)d_in[0];
    const float* Wq = (const float*)d_in[1];
    const float* bq = (const float*)d_in[2];
    const float* Wk = (const float*)d_in[3];
    const float* bk = (const float*)d_in[4];
    const float* Wv = (const float*)d_in[5];
    const float* bv = (const float*)d_in[6];
    const float* Wo = (const float*)d_in[7];
    const float* bo = (const float*)d_in[8];
    const float* W1 = (const float*)d_in[9];
    const float* b1 = (const float*)d_in[10];
    const float* Wm = (const float*)d_in[11];
    const float* bm = (const float*)d_in[12];
    const float* W2 = (const float*)d_in[13];
    const float* b2 = (const float*)d_in[14];
    const float* g1 = (const float*)d_in[15];
    const float* be1 = (const float*)d_in[16];
    const float* g2 = (const float*)d_in[17];
    const float* be2 = (const float*)d_in[18];

    char* ws = (char*)d_ws;
    const size_t MB = 1024 * 1024;
    bf16* WQb = (bf16*)(ws + 0 * MB);
    bf16* WKb = (bf16*)(ws + 2 * MB);
    bf16* WVb = (bf16*)(ws + 4 * MB);
    bf16* WOb = (bf16*)(ws + 6 * MB);
    bf16* W1b = (bf16*)(ws + 8 * MB);
    bf16* WMb = (bf16*)(ws + 16 * MB);
    bf16* W2b = (bf16*)(ws + 48 * MB);
    bf16* HB  = (bf16*)(ws + 56 * MB);
    bf16* QB  = (bf16*)(ws + 64 * MB);
    bf16* KB  = (bf16*)(ws + 72 * MB);
    bf16* VT  = (bf16*)(ws + 80 * MB);
    bf16* AT  = (bf16*)(ws + 88 * MB);
    float* X1 = (float*)(ws + 96 * MB);
    bf16* F1  = (bf16*)(ws + 112 * MB);
    bf16* F2  = (bf16*)(ws + 144 * MB);
    bf16* SCb = (bf16*)(ws + 96 * MB);

    float* out_x  = (float*)d_out;
    float* scores = out_x + 4194304;

    F2BP fp;
    fp.src[0] = Wq; fp.dst[0] = WQb; fp.n4[0] = 262144;
    fp.src[1] = Wk; fp.dst[1] = WKb; fp.n4[1] = 262144;
    fp.src[2] = Wv; fp.dst[2] = WVb; fp.n4[2] = 262144;
    fp.src[3] = Wo; fp.dst[3] = WOb; fp.n4[3] = 262144;
    fp.src[4] = W1; fp.dst[4] = W1b; fp.n4[4] = 1048576;
    fp.src[5] = Wm; fp.dst[5] = WMb; fp.n4[5] = 4194304;
    fp.src[6] = W2; fp.dst[6] = W2b; fp.n4[6] = 1048576;
    hipLaunchKernelGGL(f2b_multi, dim3(1024, 7), dim3(256), 0, stream, fp);

    hipLaunchKernelGGL(ln_kernel, dim3(4096), dim3(256), 0, stream, x, g1, be1, HB);

    gemm128p<1024,1024,1024,1024,1,0,1><<<dim3(8,32,1), 512, 0, stream>>>(
        HB, WQb, nullptr, QB, bq, nullptr);
    gemm128p<1024,1024,1024,1024,1,0,1><<<dim3(8,32,1), 512, 0, stream>>>(
        HB, WKb, nullptr, KB, bk, nullptr);
    gemm128p<1024,1024,1024,4096,2,0,1><<<dim3(32,8,1), 512, 0, stream>>>(
        WVb, HB, nullptr, VT, bv, nullptr);

    hipLaunchKernelGGL(qk_kernel, dim3(8,8,64), dim3(256), 0, stream, QB, KB, SCb);

    hipLaunchKernelGGL(topk_softmax, dim3(16384), dim3(256), 0, stream,
                       (unsigned short*)SCb, scores);

    hipLaunchKernelGGL(attnv_kernel, dim3(1,8,64), dim3(256), 0, stream,
                       SCb, VT, AT);

    gemm128p<1024,1024,1024,1024,1,0,1><<<dim3(8,32,1), 512, 0, stream>>>(
        AT, WOb, X1, nullptr, bo, x);

    hipLaunchKernelGGL(ln_kernel, dim3(4096), dim3(256), 0, stream, X1, g2, be2, HB);

    gemm128p<1024,1024,1024,4096,1,1,1><<<dim3(32,32,1), 512, 0, stream>>>(
        HB, W1b, nullptr, F1, b1, nullptr);
    gemm256<4096,4096,4096,4096><<<dim3(16,16,1), 512, 0, stream>>>(F1, WMb, F2, bm);

    gemm128p<4096,4096,4096,1024,1,0,1><<<dim3(8,32,1), 512, 0, stream>>>(
        F2, W2b, out_x, nullptr, b2, X1);
}